// Round 10
// baseline (613.557 us; speedup 1.0000x reference)
//
#include <hip/hip_runtime.h>
#include <cstddef>
#include <cstdint>
#include <math.h>

#define N_NODES 50000
#define N_EDGES 1600000
#define IN_C 512
#define HID_C 256
#define OUT_C 50
#define PAD_C 64
#define NUM_LAYERS 10
#define NBUCK 98          // ceil(50000/512) row-buckets
#define BSHIFT 9          // 512 rows per bucket
#define BCAP 20480        // mean 16327 + 32 sigma — overflow unreachable
#define PHB_CHUNK 8192    // edges per block in bucket_scatter
#define PHB_BLOCKS 196    // ceil(N_EDGES / PHB_CHUNK)
#define TW_BLOCKS 128     // transpose_w1: 16 k-tiles x 8 n-tiles
#define PW_BLOCKS 64      // pad_w2: 16384 / 256
#define GEMM_BLOCKS 782   // ceil(N_NODES / 64)

typedef __attribute__((ext_vector_type(8))) short short8;    // 8 bf16 (4 VGPRs)
typedef __attribute__((ext_vector_type(4))) float floatx4;   // MFMA C/D frag

__device__ inline unsigned short f2bf(float f) {             // RNE fp32->bf16
    unsigned int u = __float_as_uint(f);
    u += 0x7fffu + ((u >> 16) & 1u);
    return (unsigned short)(u >> 16);
}

__device__ inline unsigned cvtpk(float lo, float hi) {       // 2xf32 -> packed bf16x2 (RNE)
    unsigned r;
    asm("v_cvt_pk_bf16_f32 %0, %1, %2" : "=v"(r) : "v"(lo), "v"(hi));
    return r;
}

__device__ inline short8 pack_bf16x8(float4 lo, float4 hi) {
    union { unsigned u[4]; short8 s; } r;
    r.u[0] = cvtpk(lo.x, lo.y);
    r.u[1] = cvtpk(lo.z, lo.w);
    r.u[2] = cvtpk(hi.x, hi.y);
    r.u[3] = cvtpk(hi.z, hi.w);
    return r.s;
}

// async 16B global->LDS (LDS dest is wave-uniform base + lane*16)
#define ASYNC16(g, l)                                                     \
    __builtin_amdgcn_global_load_lds(                                     \
        (const __attribute__((address_space(1))) void*)(g),               \
        (__attribute__((address_space(3))) void*)(l), 16, 0, 0)

#define WAITCNT6() asm volatile("s_waitcnt vmcnt(6)" ::: "memory")
#define WAITCNT0() asm volatile("s_waitcnt vmcnt(0)" ::: "memory")
#define SBAR()     __builtin_amdgcn_s_barrier()

// ---------------------------------------------------------------------------
// K1 prep_fused: three independent prep kernels in one launch (block ranges).
//   [0,196)      bucket_scatter  (edge -> row-bucket scatter, LDS counts)
//   [196,324)    transpose_w1    (W1 fp32 -> Wt bf16 transposed)
//   [324,388)    pad_w2          (W2 -> Wpt bf16 transposed+padded, b2 -> bp)
// ---------------------------------------------------------------------------
__global__ __launch_bounds__(256) void prep_fused(const int* __restrict__ erow,
                                                  const int* __restrict__ ecol,
                                                  const float* __restrict__ ew,
                                                  int* __restrict__ bfill,
                                                  uint2* __restrict__ buckets,
                                                  const float* __restrict__ W1,
                                                  unsigned short* __restrict__ Wt,
                                                  const float* __restrict__ W2,
                                                  const float* __restrict__ b2,
                                                  unsigned short* __restrict__ Wpt,
                                                  float* __restrict__ bp) {
    __shared__ int  lcnt[NBUCK];
    __shared__ int  lbase[NBUCK];
    __shared__ float tile[32][33];
    const int bid = blockIdx.x;
    const int t = threadIdx.x;

    if (bid < PHB_BLOCKS) {
        // ---- bucket_scatter ----
        for (int b = t; b < NBUCK; b += 256) lcnt[b] = 0;
        __syncthreads();
        const int e0 = bid * PHB_CHUNK;
        const int e1 = min(e0 + PHB_CHUNK, N_EDGES);
        for (int e = e0 + t; e < e1; e += 256)
            atomicAdd(&lcnt[erow[e] >> BSHIFT], 1);
        __syncthreads();
        for (int b = t; b < NBUCK; b += 256) {
            lbase[b] = atomicAdd(&bfill[b], lcnt[b]);
            lcnt[b] = 0;
        }
        __syncthreads();
        for (int e = e0 + t; e < e1; e += 256) {
            int r = erow[e];
            int b = r >> BSHIFT;
            int o = atomicAdd(&lcnt[b], 1);
            int idx = lbase[b] + o;
            if (idx < BCAP) {   // BCAP = mean + 32 sigma: always true
                unsigned packed = ((unsigned)(r - (b << BSHIFT)) << 17) | (unsigned)ecol[e];
                buckets[(size_t)b * BCAP + idx] = make_uint2(packed, __float_as_uint(ew[e]));
            }
        }
    } else if (bid < PHB_BLOCKS + TW_BLOCKS) {
        // ---- transpose_w1 ----
        int tb = bid - PHB_BLOCKS;
        int bx = tb & 15;              // k-tile (16)
        int by = tb >> 4;              // n-tile (8)
        int tx = t & 31, ty = t >> 5;  // 32 x 8
#pragma unroll
        for (int i = 0; i < 32; i += 8)
            tile[ty + i][tx] = W1[(bx * 32 + ty + i) * HID_C + by * 32 + tx];
        __syncthreads();
#pragma unroll
        for (int i = 0; i < 32; i += 8)
            Wt[(size_t)(by * 32 + ty + i) * IN_C + bx * 32 + tx] = f2bf(tile[tx][ty + i]);
    } else {
        // ---- pad_w2 ----
        int idx = (bid - PHB_BLOCKS - TW_BLOCKS) * 256 + t;
        if (idx < PAD_C * HID_C) {
            int n = idx >> 8, k = idx & 255;
            float v = (n < OUT_C) ? W2[k * OUT_C + n] : 0.f;
            Wpt[idx] = f2bf(v);
        }
        if (idx < PAD_C) bp[idx] = (idx < OUT_C) ? b2[idx] : 0.f;
    }
}

__global__ __launch_bounds__(128) void bucket_scan(const int* __restrict__ bfill,
                                                   int* __restrict__ bbase,
                                                   int* __restrict__ rowptr) {
    __shared__ int sd[128];
    int t = threadIdx.x;
    int v = (t < NBUCK) ? min(bfill[t], BCAP) : 0;
    sd[t] = v;
    __syncthreads();
    for (int off = 1; off < 128; off <<= 1) {
        int x = (t >= off) ? sd[t - off] : 0;
        __syncthreads();
        sd[t] += x;
        __syncthreads();
    }
    if (t < NBUCK) bbase[t] = sd[t] - v;
    if (t == NBUCK - 1) {
        bbase[NBUCK] = sd[t];
        rowptr[N_NODES] = sd[t];
    }
}

// ---------------------------------------------------------------------------
// K2 csr_gemm_fused: bucket_csr (blocks [0,98)) runs CONCURRENTLY with the
// R9-proven gemm pipeline (blocks [98,880)) — no data dependency; previously
// the stream serialized ~25us of CSR on a 38%-occupied GPU under nothing.
// gemm body identical to R9 (74us verified): 3-buffer counted-vmcnt pipeline,
// double-sided B chunk swizzle, fused GEMM2 epilogue, bf16-only h0b output.
// ---------------------------------------------------------------------------
__global__ __launch_bounds__(256) void csr_gemm_fused(
        // csr part
        const uint2* __restrict__ buckets, const int* __restrict__ bfill,
        const int* __restrict__ bbase, int* __restrict__ rowptr,
        uint2* __restrict__ edges,
        // gemm part
        const float* __restrict__ A, const unsigned short* __restrict__ Wt,
        const float* __restrict__ b1, const unsigned short* __restrict__ Wpt,
        const float* __restrict__ bp, unsigned short* __restrict__ h0b) {
    __shared__ __align__(16) char smem[73728];
    const int bid = blockIdx.x;
    const int tid = threadIdx.x;

    if (bid < NBUCK) {
        // ================= bucket_csr =================
        int* hist = (int*)smem;               // 512 ints
        int* excl = (int*)(smem + 2048);      // 512 ints
        int* psum = (int*)(smem + 4096);      // 256 ints
        const int b = bid;
        const int t = tid;
        const int n = min(bfill[b], BCAP);
        const uint2* bk = buckets + (size_t)b * BCAP;

        hist[t] = 0; hist[t + 256] = 0;
        __syncthreads();
        for (int i = t; i < n; i += 256)
            atomicAdd(&hist[bk[i].x >> 17], 1);
        __syncthreads();
        int a0 = hist[2 * t], a1 = hist[2 * t + 1];
        psum[t] = a0 + a1;
        __syncthreads();
        for (int off = 1; off < 256; off <<= 1) {
            int x = (t >= off) ? psum[t - off] : 0;
            __syncthreads();
            psum[t] += x;
            __syncthreads();
        }
        int pe = psum[t] - (a0 + a1);
        excl[2 * t] = pe;
        excl[2 * t + 1] = pe + a0;
        __syncthreads();
        const int base = bbase[b];
#pragma unroll
        for (int k = 0; k < 2; ++k) {
            int lr = t + k * 256;
            int r = (b << BSHIFT) + lr;
            if (r < N_NODES) rowptr[r] = base + excl[lr];
        }
        hist[t] = 0; hist[t + 256] = 0;
        __syncthreads();
        for (int i = t; i < n; i += 256) {
            uint2 ed = bk[i];
            int lr = ed.x >> 17;
            int pos = base + excl[lr] + atomicAdd(&hist[lr], 1);
            edges[pos] = make_uint2(ed.x & 0x1FFFFu, ed.y);
        }
        return;
    }

    // ================= gemm1_fused (R9 body) =================
    float*          Ab[3] = {(float*)smem,
                             (float*)(smem + 24576),
                             (float*)(smem + 49152)};
    unsigned short* Bb[3] = {(unsigned short*)(smem + 8192),
                             (unsigned short*)(smem + 32768),
                             (unsigned short*)(smem + 57344)};
    unsigned short* Hs = (unsigned short*)smem;    // [64][264] bf16 (reused)
    const int HS_LD = 264;

    const int wave = tid >> 6, lane = tid & 63;
    const int quad = lane >> 4, l16 = lane & 15;
    const int m0 = (bid - NBUCK) * 64;
    const int wm = (wave >> 1) * 32;               // row offset of this wave
    const int wn = (wave & 1) * 128;               // col offset of this wave

    floatx4 acc[2][8];
#pragma unroll
    for (int i = 0; i < 2; ++i)
#pragma unroll
        for (int j = 0; j < 8; ++j) acc[i][j] = (floatx4){0.f, 0.f, 0.f, 0.f};

    auto stage = [&](int bi, int ks) {
        const int k0 = ks << 5;
#pragma unroll
        for (int j = 0; j < 2; ++j) {
            int slot = tid + j * 256;
            int r = slot >> 3, c = slot & 7;
            int gr = m0 + r;
            if (gr >= N_NODES) gr = N_NODES - 1;   // clamp: finite garbage, masked later
            const float* src = A + (size_t)gr * IN_C + k0 + ((c ^ (r & 7)) << 2);
            ASYNC16(src, Ab[bi] + (slot << 2));
        }
#pragma unroll
        for (int j = 0; j < 4; ++j) {              // row-major: slot=(n,c), 16B chunks
            int slot = tid + j * 256;              // 0..1023
            int n = slot >> 2, c = slot & 3;
            int cs = c ^ ((n >> 1) & 3);           // source-side swizzle (64B-local)
            const unsigned short* src = Wt + (size_t)n * IN_C + k0 + (cs << 3);
            ASYNC16(src, Bb[bi] + (slot << 3));    // LDS linear in slot
        }
    };

    auto compute = [&](int bi) {
        const float* As_ = Ab[bi];
        const unsigned short* Bs_ = Bb[bi];
        short8 bfr[8], afr[2];
#pragma unroll
        for (int nt = 0; nt < 8; ++nt) {
            int n  = wn + nt * 16 + l16;
            int cq = quad ^ ((n >> 1) & 3);        // read-side swizzle (same involution)
            bfr[nt] = *(const short8*)&Bs_[(n << 5) + (cq << 3)];
        }
#pragma unroll
        for (int mt = 0; mt < 2; ++mt) {
            int r  = wm + mt * 16 + l16;
            int rx = r & 7;
            float4 lo = *(const float4*)&As_[(r << 5) + (((2 * quad)     ^ rx) << 2)];
            float4 hi = *(const float4*)&As_[(r << 5) + (((2 * quad + 1) ^ rx) << 2)];
            afr[mt] = pack_bf16x8(lo, hi);
        }
#pragma unroll
        for (int mt = 0; mt < 2; ++mt)
#pragma unroll
            for (int nt = 0; nt < 8; ++nt)
                acc[mt][nt] = __builtin_amdgcn_mfma_f32_16x16x32_bf16(afr[mt], bfr[nt],
                                                                      acc[mt][nt], 0, 0, 0);
    };

    // --- pipelined main loop: 16 K-steps, 3 buffers, depth-2 prefetch ------
    stage(0, 0);
    stage(1, 1);
#pragma unroll
    for (int ks = 0; ks < 14; ++ks) {
        WAITCNT6();                    // buf ks%3 landed (only ks+1's 6 in flight)
        SBAR();                        // all waves: buf ks ready; buf (ks+2)%3 free
        stage((ks + 2) % 3, ks + 2);   // async; needed 2 iterations from now
        compute(ks % 3);
    }
    WAITCNT6(); SBAR(); compute(2);    // ks=14
    WAITCNT0(); SBAR(); compute(0);    // ks=15 (drain)
    __syncthreads();                   // before Hs overlays buffers

    // --- stage relu(h + b1) to LDS bf16 (row = quad*4+r, col = l16 map) ----
#pragma unroll
    for (int nt = 0; nt < 8; ++nt) {
        int n = wn + nt * 16 + l16;
        float bn = b1[n];
#pragma unroll
        for (int mt = 0; mt < 2; ++mt)
#pragma unroll
            for (int r = 0; r < 4; ++r) {
                float v = acc[mt][nt][r] + bn;
                v = v > 0.f ? v : 0.f;
                Hs[(wm + mt * 16 + quad * 4 + r) * HS_LD + n] = f2bf(v);
            }
    }
    __syncthreads();

    // --- fused GEMM2: h0[64,64] = Hs[64,256] @ Wpt^T + bp ------------------
    floatx4 acc2[4];
#pragma unroll
    for (int nt = 0; nt < 4; ++nt) acc2[nt] = (floatx4){0.f, 0.f, 0.f, 0.f};
    const int hrow = (wave << 4) + l16;
#pragma unroll
    for (int k2 = 0; k2 < 8; ++k2) {
        short8 haf = *(const short8*)&Hs[hrow * HS_LD + (k2 << 5) + (quad << 3)];
#pragma unroll
        for (int nt = 0; nt < 4; ++nt) {
            short8 bf = *(const short8*)&Wpt[(size_t)((nt << 4) + l16) * HID_C + (k2 << 5) + (quad << 3)];
            acc2[nt] = __builtin_amdgcn_mfma_f32_16x16x32_bf16(haf, bf, acc2[nt], 0, 0, 0);
        }
    }
#pragma unroll
    for (int nt = 0; nt < 4; ++nt) {
        int c = (nt << 4) + l16;
        float bn = bp[c];
#pragma unroll
        for (int r = 0; r < 4; ++r) {
            int row = m0 + (wave << 4) + (quad << 2) + r;
            if (row < N_NODES)
                h0b[(size_t)row * PAD_C + c] = f2bf(acc2[nt][r] + bn);
        }
    }
}

// ---------------------------------------------------------------------------
// Propagation v4 (R10): R9 body (wave-per-node, x4 unroll, launch_bounds
// (256,8), bf16 h0b residual) + NON-TEMPORAL edge loads: the 12.8 MB/layer
// edge stream is read once per layer and was evicting the 6.4 MB gather
// table from L2 (edges + table + h-bufs > 32 MB aggregate L2).
// ---------------------------------------------------------------------------
__device__ inline void edge_fma(float* acc, float wgt, uint4 hv) {
    acc[0] = fmaf(wgt, __uint_as_float(hv.x << 16),         acc[0]);
    acc[1] = fmaf(wgt, __uint_as_float(hv.x & 0xffff0000u), acc[1]);
    acc[2] = fmaf(wgt, __uint_as_float(hv.y << 16),         acc[2]);
    acc[3] = fmaf(wgt, __uint_as_float(hv.y & 0xffff0000u), acc[3]);
    acc[4] = fmaf(wgt, __uint_as_float(hv.z << 16),         acc[4]);
    acc[5] = fmaf(wgt, __uint_as_float(hv.z & 0xffff0000u), acc[5]);
    acc[6] = fmaf(wgt, __uint_as_float(hv.w << 16),         acc[6]);
    acc[7] = fmaf(wgt, __uint_as_float(hv.w & 0xffff0000u), acc[7]);
}

template <bool LAST>
__global__ __launch_bounds__(256, 8) void prop8(const int* __restrict__ rowptr,
                                                const uint2* __restrict__ edges,
                                                const unsigned short* __restrict__ hin,
                                                const unsigned short* __restrict__ h0b,
                                                unsigned short* __restrict__ hout_b,
                                                float* __restrict__ out_f) {
    int wid = (blockIdx.x * blockDim.x + threadIdx.x) >> 6;
    if (wid >= N_NODES) return;
    int lane = threadIdx.x & 63;
    int slot = lane >> 3;
    int lc   = lane & 7;
    int s = rowptr[wid], e = rowptr[wid + 1];
    const unsigned long long* e8 = (const unsigned long long*)edges;

    float acc0[8], acc1[8];
#pragma unroll
    for (int k = 0; k < 8; ++k) { acc0[k] = 0.f; acc1[k] = 0.f; }

    int i = s;
    for (; i + 32 <= e; i += 32) {
        unsigned long long c0 = __builtin_nontemporal_load(e8 + i + slot);
        unsigned long long c1 = __builtin_nontemporal_load(e8 + i + 8 + slot);
        unsigned long long c2 = __builtin_nontemporal_load(e8 + i + 16 + slot);
        unsigned long long c3 = __builtin_nontemporal_load(e8 + i + 24 + slot);
        uint4 hv0 = *(const uint4*)((const char*)hin + (((size_t)(unsigned)c0) << 7) + lc * 16);
        uint4 hv1 = *(const uint4*)((const char*)hin + (((size_t)(unsigned)c1) << 7) + lc * 16);
        uint4 hv2 = *(const uint4*)((const char*)hin + (((size_t)(unsigned)c2) << 7) + lc * 16);
        uint4 hv3 = *(const uint4*)((const char*)hin + (((size_t)(unsigned)c3) << 7) + lc * 16);
        edge_fma(acc0, __uint_as_float((unsigned)(c0 >> 32)), hv0);
        edge_fma(acc1, __uint_as_float((unsigned)(c1 >> 32)), hv1);
        edge_fma(acc0, __uint_as_float((unsigned)(c2 >> 32)), hv2);
        edge_fma(acc1, __uint_as_float((unsigned)(c3 >> 32)), hv3);
    }
    for (; i + 16 <= e; i += 16) {
        unsigned long long c0 = __builtin_nontemporal_load(e8 + i + slot);
        unsigned long long c1 = __builtin_nontemporal_load(e8 + i + 8 + slot);
        uint4 hv0 = *(const uint4*)((const char*)hin + (((size_t)(unsigned)c0) << 7) + lc * 16);
        uint4 hv1 = *(const uint4*)((const char*)hin + (((size_t)(unsigned)c1) << 7) + lc * 16);
        edge_fma(acc0, __uint_as_float((unsigned)(c0 >> 32)), hv0);
        edge_fma(acc1, __uint_as_float((unsigned)(c1 >> 32)), hv1);
    }
    for (; i < e; i += 8) {
        int idx = i + slot;
        unsigned long long c0 = (idx < e) ? __builtin_nontemporal_load(e8 + idx) : 0ull;
        float wgt = (idx < e) ? __uint_as_float((unsigned)(c0 >> 32)) : 0.f;
        uint4 hv = *(const uint4*)((const char*)hin + (((size_t)(unsigned)c0) << 7) + lc * 16);
        edge_fma(acc0, wgt, hv);
    }

    float r[8];
#pragma unroll
    for (int k = 0; k < 8; ++k) {
        float v = acc0[k] + acc1[k];
        v += __shfl_xor(v, 8, 64);
        v += __shfl_xor(v, 16, 64);
        v += __shfl_xor(v, 32, 64);
        r[k] = v;
    }

    // residual from bf16 h0b (same 8 channels this lane owns)
    uint4 h0v = *(const uint4*)((const char*)h0b + ((size_t)wid << 7) + lc * 16);
    float h0e[8];
    h0e[0] = __uint_as_float(h0v.x << 16);
    h0e[1] = __uint_as_float(h0v.x & 0xffff0000u);
    h0e[2] = __uint_as_float(h0v.y << 16);
    h0e[3] = __uint_as_float(h0v.y & 0xffff0000u);
    h0e[4] = __uint_as_float(h0v.z << 16);
    h0e[5] = __uint_as_float(h0v.z & 0xffff0000u);
    h0e[6] = __uint_as_float(h0v.w << 16);
    h0e[7] = __uint_as_float(h0v.w & 0xffff0000u);
#pragma unroll
    for (int k = 0; k < 8; ++k) r[k] = 0.9f * r[k] + 0.1f * h0e[k];

    if (!LAST) {
        if (slot == 0) {
            uint4 u;
            u.x = ((unsigned)f2bf(r[1]) << 16) | f2bf(r[0]);
            u.y = ((unsigned)f2bf(r[3]) << 16) | f2bf(r[2]);
            u.z = ((unsigned)f2bf(r[5]) << 16) | f2bf(r[4]);
            u.w = ((unsigned)f2bf(r[7]) << 16) | f2bf(r[6]);
            *(uint4*)((char*)hout_b + ((size_t)wid << 7) + lc * 16) = u;
        }
    } else {
        int ch0 = lc * 8;
        float m = -INFINITY;
#pragma unroll
        for (int k = 0; k < 8; ++k) if (ch0 + k < OUT_C) m = fmaxf(m, r[k]);
        m = fmaxf(m, __shfl_xor(m, 1, 64));
        m = fmaxf(m, __shfl_xor(m, 2, 64));
        m = fmaxf(m, __shfl_xor(m, 4, 64));
        float ss = 0.f;
#pragma unroll
        for (int k = 0; k < 8; ++k) if (ch0 + k < OUT_C) ss += __expf(r[k] - m);
        ss += __shfl_xor(ss, 1, 64);
        ss += __shfl_xor(ss, 2, 64);
        ss += __shfl_xor(ss, 4, 64);
        float lse = __logf(ss);
        if (slot == 0) {
#pragma unroll
            for (int k = 0; k < 8; ++k)
                if (ch0 + k < OUT_C)
                    out_f[(size_t)wid * OUT_C + ch0 + k] = (r[k] - m) - lse;
        }
    }
}

// ---------------------------------------------------------------------------
extern "C" void kernel_launch(void* const* d_in, const int* in_sizes, int n_in,
                              void* d_out, int out_size, void* d_ws, size_t ws_size,
                              hipStream_t stream) {
    const float* x    = (const float*)d_in[0];
    const int*   erow = (const int*)d_in[1];
    const int*   ecol = (const int*)d_in[2];
    const float* ew   = (const float*)d_in[3];
    const float* W1   = (const float*)d_in[4];
    const float* b1   = (const float*)d_in[5];
    const float* W2   = (const float*)d_in[6];
    const float* b2   = (const float*)d_in[7];
    float* out = (float*)d_out;

    char* p = (char*)d_ws;
    auto alloc = [&](size_t bytes) {
        char* r = p;
        p += (bytes + 255) & ~(size_t)255;
        return r;
    };
    char*  scratch = alloc((size_t)NBUCK * BCAP * 8);             // 16.1 MB (buckets / ha / hb)
    unsigned short* h0b = (unsigned short*)alloc((size_t)N_NODES * PAD_C * 2); // 6.4 MB
    uint2* edges  = (uint2*)alloc((size_t)N_EDGES * 8);           // 12.8 MB packed CSR
    int*   rowptr = (int*)alloc((size_t)(N_NODES + 1) * 4);
    int*   bfill  = (int*)alloc((size_t)NBUCK * 4);
    int*   bbase  = (int*)alloc((size_t)(NBUCK + 1) * 4);
    float* bp     = (float*)alloc((size_t)PAD_C * 4);
    unsigned short* Wt  = (unsigned short*)alloc((size_t)HID_C * IN_C * 2);
    unsigned short* Wpt = (unsigned short*)alloc((size_t)PAD_C * HID_C * 2);
    // --- aliases onto scratch (sequential lifetimes, stream-ordered):
    uint2* buckets = (uint2*)scratch;                                       // CSR build
    unsigned short* ha = (unsigned short*)scratch;                          // 6.4 MB (prop)
    unsigned short* hb = (unsigned short*)(scratch + (size_t)N_NODES * PAD_C * 2); // 6.4 MB

    hipMemsetAsync(bfill, 0, (size_t)NBUCK * 4, stream);

    // K1: scatter + transpose_w1 + pad_w2 (independent, one launch)
    prep_fused<<<PHB_BLOCKS + TW_BLOCKS + PW_BLOCKS, 256, 0, stream>>>(
        erow, ecol, ew, bfill, buckets, W1, Wt, W2, b2, Wpt, bp);

    bucket_scan<<<1, 128, 0, stream>>>(bfill, bbase, rowptr);

    // K2: bucket_csr (98 blocks) overlapped with gemm (782 blocks)
    csr_gemm_fused<<<NBUCK + GEMM_BLOCKS, 256, 0, stream>>>(
        buckets, bfill, bbase, rowptr, edges,
        x, Wt, b1, Wpt, bp, h0b);

    // Propagation x10: separate launches, wave-per-node, bf16 ping-pong.
    const int prop_blocks = (N_NODES * 64 + 255) / 256;
    const unsigned short* cur = h0b;
    unsigned short* nxt = ha;
    for (int l = 0; l < NUM_LAYERS - 1; ++l) {
        prop8<false><<<prop_blocks, 256, 0, stream>>>(rowptr, edges, cur, h0b,
                                                      nxt, nullptr);
        const unsigned short* t = nxt;
        nxt = (nxt == ha) ? hb : ha;
        cur = t;
    }
    prop8<true><<<prop_blocks, 256, 0, stream>>>(rowptr, edges, cur, h0b,
                                                 nullptr, out);
}

// Round 11
// 560.782 us; speedup vs baseline: 1.0941x; 1.0941x over previous
//
#include <hip/hip_runtime.h>
#include <cstddef>
#include <cstdint>
#include <math.h>

#define N_NODES 50000
#define N_EDGES 1600000
#define IN_C 512
#define HID_C 256
#define OUT_C 50
#define PAD_C 64
#define NUM_LAYERS 10
#define NBUCK 98          // ceil(50000/512) row-buckets
#define BSHIFT 9          // 512 rows per bucket
#define BCAP 20480        // mean 16327 + 32 sigma — overflow unreachable
#define PHB_CHUNK 8192    // edges per block in bucket_scatter
#define PHB_BLOCKS 196    // ceil(N_EDGES / PHB_CHUNK)
#define TW_BLOCKS 128     // transpose_w1: 16 k-tiles x 8 n-tiles
#define PW_BLOCKS 64      // pad_w2: 16384 / 256
#define GEMM_BLOCKS 782   // ceil(N_NODES / 64)

typedef __attribute__((ext_vector_type(8))) short short8;    // 8 bf16 (4 VGPRs)
typedef __attribute__((ext_vector_type(4))) float floatx4;   // MFMA C/D frag

__device__ inline unsigned short f2bf(float f) {             // RNE fp32->bf16
    unsigned int u = __float_as_uint(f);
    u += 0x7fffu + ((u >> 16) & 1u);
    return (unsigned short)(u >> 16);
}

__device__ inline unsigned cvtpk(float lo, float hi) {       // 2xf32 -> packed bf16x2 (RNE)
    unsigned r;
    asm("v_cvt_pk_bf16_f32 %0, %1, %2" : "=v"(r) : "v"(lo), "v"(hi));
    return r;
}

__device__ inline short8 pack_bf16x8(float4 lo, float4 hi) {
    union { unsigned u[4]; short8 s; } r;
    r.u[0] = cvtpk(lo.x, lo.y);
    r.u[1] = cvtpk(lo.z, lo.w);
    r.u[2] = cvtpk(hi.x, hi.y);
    r.u[3] = cvtpk(hi.z, hi.w);
    return r.s;
}

// async 16B global->LDS (LDS dest is wave-uniform base + lane*16)
#define ASYNC16(g, l)                                                     \
    __builtin_amdgcn_global_load_lds(                                     \
        (const __attribute__((address_space(1))) void*)(g),               \
        (__attribute__((address_space(3))) void*)(l), 16, 0, 0)

#define WAITCNT6() asm volatile("s_waitcnt vmcnt(6)" ::: "memory")
#define WAITCNT0() asm volatile("s_waitcnt vmcnt(0)" ::: "memory")
#define SBAR()     __builtin_amdgcn_s_barrier()

// ---------------------------------------------------------------------------
// K1 prep_fused (R10-verified): three independent prep kernels, block ranges.
//   [0,196)      bucket_scatter
//   [196,324)    transpose_w1
//   [324,388)    pad_w2
// ---------------------------------------------------------------------------
__global__ __launch_bounds__(256) void prep_fused(const int* __restrict__ erow,
                                                  const int* __restrict__ ecol,
                                                  const float* __restrict__ ew,
                                                  int* __restrict__ bfill,
                                                  uint2* __restrict__ buckets,
                                                  const float* __restrict__ W1,
                                                  unsigned short* __restrict__ Wt,
                                                  const float* __restrict__ W2,
                                                  const float* __restrict__ b2,
                                                  unsigned short* __restrict__ Wpt,
                                                  float* __restrict__ bp) {
    __shared__ int  lcnt[NBUCK];
    __shared__ int  lbase[NBUCK];
    __shared__ float tile[32][33];
    const int bid = blockIdx.x;
    const int t = threadIdx.x;

    if (bid < PHB_BLOCKS) {
        // ---- bucket_scatter ----
        for (int b = t; b < NBUCK; b += 256) lcnt[b] = 0;
        __syncthreads();
        const int e0 = bid * PHB_CHUNK;
        const int e1 = min(e0 + PHB_CHUNK, N_EDGES);
        for (int e = e0 + t; e < e1; e += 256)
            atomicAdd(&lcnt[erow[e] >> BSHIFT], 1);
        __syncthreads();
        for (int b = t; b < NBUCK; b += 256) {
            lbase[b] = atomicAdd(&bfill[b], lcnt[b]);
            lcnt[b] = 0;
        }
        __syncthreads();
        for (int e = e0 + t; e < e1; e += 256) {
            int r = erow[e];
            int b = r >> BSHIFT;
            int o = atomicAdd(&lcnt[b], 1);
            int idx = lbase[b] + o;
            if (idx < BCAP) {   // BCAP = mean + 32 sigma: always true
                unsigned packed = ((unsigned)(r - (b << BSHIFT)) << 17) | (unsigned)ecol[e];
                buckets[(size_t)b * BCAP + idx] = make_uint2(packed, __float_as_uint(ew[e]));
            }
        }
    } else if (bid < PHB_BLOCKS + TW_BLOCKS) {
        // ---- transpose_w1 ----
        int tb = bid - PHB_BLOCKS;
        int bx = tb & 15;              // k-tile (16)
        int by = tb >> 4;              // n-tile (8)
        int tx = t & 31, ty = t >> 5;  // 32 x 8
#pragma unroll
        for (int i = 0; i < 32; i += 8)
            tile[ty + i][tx] = W1[(bx * 32 + ty + i) * HID_C + by * 32 + tx];
        __syncthreads();
#pragma unroll
        for (int i = 0; i < 32; i += 8)
            Wt[(size_t)(by * 32 + ty + i) * IN_C + bx * 32 + tx] = f2bf(tile[tx][ty + i]);
    } else {
        // ---- pad_w2 ----
        int idx = (bid - PHB_BLOCKS - TW_BLOCKS) * 256 + t;
        if (idx < PAD_C * HID_C) {
            int n = idx >> 8, k = idx & 255;
            float v = (n < OUT_C) ? W2[k * OUT_C + n] : 0.f;
            Wpt[idx] = f2bf(v);
        }
        if (idx < PAD_C) bp[idx] = (idx < OUT_C) ? b2[idx] : 0.f;
    }
}

__global__ __launch_bounds__(128) void bucket_scan(const int* __restrict__ bfill,
                                                   int* __restrict__ bbase,
                                                   int* __restrict__ rowptr) {
    __shared__ int sd[128];
    int t = threadIdx.x;
    int v = (t < NBUCK) ? min(bfill[t], BCAP) : 0;
    sd[t] = v;
    __syncthreads();
    for (int off = 1; off < 128; off <<= 1) {
        int x = (t >= off) ? sd[t - off] : 0;
        __syncthreads();
        sd[t] += x;
        __syncthreads();
    }
    if (t < NBUCK) bbase[t] = sd[t] - v;
    if (t == NBUCK - 1) {
        bbase[NBUCK] = sd[t];
        rowptr[N_NODES] = sd[t];
    }
}

// ---------------------------------------------------------------------------
// K2 csr_gemm_fused (R10-verified, 84us = csr 25us hidden under gemm 74us):
// bucket_csr blocks [0,98) concurrent with gemm blocks [98,880).
// ---------------------------------------------------------------------------
__global__ __launch_bounds__(256) void csr_gemm_fused(
        // csr part
        const uint2* __restrict__ buckets, const int* __restrict__ bfill,
        const int* __restrict__ bbase, int* __restrict__ rowptr,
        uint2* __restrict__ edges,
        // gemm part
        const float* __restrict__ A, const unsigned short* __restrict__ Wt,
        const float* __restrict__ b1, const unsigned short* __restrict__ Wpt,
        const float* __restrict__ bp, unsigned short* __restrict__ h0b) {
    __shared__ __align__(16) char smem[73728];
    const int bid = blockIdx.x;
    const int tid = threadIdx.x;

    if (bid < NBUCK) {
        // ================= bucket_csr =================
        int* hist = (int*)smem;               // 512 ints
        int* excl = (int*)(smem + 2048);      // 512 ints
        int* psum = (int*)(smem + 4096);      // 256 ints
        const int b = bid;
        const int t = tid;
        const int n = min(bfill[b], BCAP);
        const uint2* bk = buckets + (size_t)b * BCAP;

        hist[t] = 0; hist[t + 256] = 0;
        __syncthreads();
        for (int i = t; i < n; i += 256)
            atomicAdd(&hist[bk[i].x >> 17], 1);
        __syncthreads();
        int a0 = hist[2 * t], a1 = hist[2 * t + 1];
        psum[t] = a0 + a1;
        __syncthreads();
        for (int off = 1; off < 256; off <<= 1) {
            int x = (t >= off) ? psum[t - off] : 0;
            __syncthreads();
            psum[t] += x;
            __syncthreads();
        }
        int pe = psum[t] - (a0 + a1);
        excl[2 * t] = pe;
        excl[2 * t + 1] = pe + a0;
        __syncthreads();
        const int base = bbase[b];
#pragma unroll
        for (int k = 0; k < 2; ++k) {
            int lr = t + k * 256;
            int r = (b << BSHIFT) + lr;
            if (r < N_NODES) rowptr[r] = base + excl[lr];
        }
        hist[t] = 0; hist[t + 256] = 0;
        __syncthreads();
        for (int i = t; i < n; i += 256) {
            uint2 ed = bk[i];
            int lr = ed.x >> 17;
            int pos = base + excl[lr] + atomicAdd(&hist[lr], 1);
            edges[pos] = make_uint2(ed.x & 0x1FFFFu, ed.y);
        }
        return;
    }

    // ================= gemm1_fused (R9 body, 74us verified) =================
    float*          Ab[3] = {(float*)smem,
                             (float*)(smem + 24576),
                             (float*)(smem + 49152)};
    unsigned short* Bb[3] = {(unsigned short*)(smem + 8192),
                             (unsigned short*)(smem + 32768),
                             (unsigned short*)(smem + 57344)};
    unsigned short* Hs = (unsigned short*)smem;    // [64][264] bf16 (reused)
    const int HS_LD = 264;

    const int wave = tid >> 6, lane = tid & 63;
    const int quad = lane >> 4, l16 = lane & 15;
    const int m0 = (bid - NBUCK) * 64;
    const int wm = (wave >> 1) * 32;               // row offset of this wave
    const int wn = (wave & 1) * 128;               // col offset of this wave

    floatx4 acc[2][8];
#pragma unroll
    for (int i = 0; i < 2; ++i)
#pragma unroll
        for (int j = 0; j < 8; ++j) acc[i][j] = (floatx4){0.f, 0.f, 0.f, 0.f};

    auto stage = [&](int bi, int ks) {
        const int k0 = ks << 5;
#pragma unroll
        for (int j = 0; j < 2; ++j) {
            int slot = tid + j * 256;
            int r = slot >> 3, c = slot & 7;
            int gr = m0 + r;
            if (gr >= N_NODES) gr = N_NODES - 1;   // clamp: finite garbage, masked later
            const float* src = A + (size_t)gr * IN_C + k0 + ((c ^ (r & 7)) << 2);
            ASYNC16(src, Ab[bi] + (slot << 2));
        }
#pragma unroll
        for (int j = 0; j < 4; ++j) {              // row-major: slot=(n,c), 16B chunks
            int slot = tid + j * 256;              // 0..1023
            int n = slot >> 2, c = slot & 3;
            int cs = c ^ ((n >> 1) & 3);           // source-side swizzle (64B-local)
            const unsigned short* src = Wt + (size_t)n * IN_C + k0 + (cs << 3);
            ASYNC16(src, Bb[bi] + (slot << 3));    // LDS linear in slot
        }
    };

    auto compute = [&](int bi) {
        const float* As_ = Ab[bi];
        const unsigned short* Bs_ = Bb[bi];
        short8 bfr[8], afr[2];
#pragma unroll
        for (int nt = 0; nt < 8; ++nt) {
            int n  = wn + nt * 16 + l16;
            int cq = quad ^ ((n >> 1) & 3);        // read-side swizzle (same involution)
            bfr[nt] = *(const short8*)&Bs_[(n << 5) + (cq << 3)];
        }
#pragma unroll
        for (int mt = 0; mt < 2; ++mt) {
            int r  = wm + mt * 16 + l16;
            int rx = r & 7;
            float4 lo = *(const float4*)&As_[(r << 5) + (((2 * quad)     ^ rx) << 2)];
            float4 hi = *(const float4*)&As_[(r << 5) + (((2 * quad + 1) ^ rx) << 2)];
            afr[mt] = pack_bf16x8(lo, hi);
        }
#pragma unroll
        for (int mt = 0; mt < 2; ++mt)
#pragma unroll
            for (int nt = 0; nt < 8; ++nt)
                acc[mt][nt] = __builtin_amdgcn_mfma_f32_16x16x32_bf16(afr[mt], bfr[nt],
                                                                      acc[mt][nt], 0, 0, 0);
    };

    // --- pipelined main loop: 16 K-steps, 3 buffers, depth-2 prefetch ------
    stage(0, 0);
    stage(1, 1);
#pragma unroll
    for (int ks = 0; ks < 14; ++ks) {
        WAITCNT6();                    // buf ks%3 landed (only ks+1's 6 in flight)
        SBAR();                        // all waves: buf ks ready; buf (ks+2)%3 free
        stage((ks + 2) % 3, ks + 2);   // async; needed 2 iterations from now
        compute(ks % 3);
    }
    WAITCNT6(); SBAR(); compute(2);    // ks=14
    WAITCNT0(); SBAR(); compute(0);    // ks=15 (drain)
    __syncthreads();                   // before Hs overlays buffers

    // --- stage relu(h + b1) to LDS bf16 (row = quad*4+r, col = l16 map) ----
#pragma unroll
    for (int nt = 0; nt < 8; ++nt) {
        int n = wn + nt * 16 + l16;
        float bn = b1[n];
#pragma unroll
        for (int mt = 0; mt < 2; ++mt)
#pragma unroll
            for (int r = 0; r < 4; ++r) {
                float v = acc[mt][nt][r] + bn;
                v = v > 0.f ? v : 0.f;
                Hs[(wm + mt * 16 + quad * 4 + r) * HS_LD + n] = f2bf(v);
            }
    }
    __syncthreads();

    // --- fused GEMM2: h0[64,64] = Hs[64,256] @ Wpt^T + bp ------------------
    floatx4 acc2[4];
#pragma unroll
    for (int nt = 0; nt < 4; ++nt) acc2[nt] = (floatx4){0.f, 0.f, 0.f, 0.f};
    const int hrow = (wave << 4) + l16;
#pragma unroll
    for (int k2 = 0; k2 < 8; ++k2) {
        short8 haf = *(const short8*)&Hs[hrow * HS_LD + (k2 << 5) + (quad << 3)];
#pragma unroll
        for (int nt = 0; nt < 4; ++nt) {
            short8 bf = *(const short8*)&Wpt[(size_t)((nt << 4) + l16) * HID_C + (k2 << 5) + (quad << 3)];
            acc2[nt] = __builtin_amdgcn_mfma_f32_16x16x32_bf16(haf, bf, acc2[nt], 0, 0, 0);
        }
    }
#pragma unroll
    for (int nt = 0; nt < 4; ++nt) {
        int c = (nt << 4) + l16;
        float bn = bp[c];
#pragma unroll
        for (int r = 0; r < 4; ++r) {
            int row = m0 + (wave << 4) + (quad << 2) + r;
            if (row < N_NODES)
                h0b[(size_t)row * PAD_C + c] = f2bf(acc2[nt][r] + bn);
        }
    }
}

// ---------------------------------------------------------------------------
// Propagation (R9-exact body, best measured 46us/layer): wave-per-node,
// x4 unroll, launch_bounds(256,8), bf16 h0b residual, REGULAR edge loads
// (R10's non-temporal loads cost +3us/layer — edges were partially L2-
// resident across layers; the gather table can't be (6.4MB > 4MB/XCD L2),
// so protecting it bought nothing).
// ---------------------------------------------------------------------------
__device__ inline void edge_fma(float* acc, float wgt, uint4 hv) {
    acc[0] = fmaf(wgt, __uint_as_float(hv.x << 16),         acc[0]);
    acc[1] = fmaf(wgt, __uint_as_float(hv.x & 0xffff0000u), acc[1]);
    acc[2] = fmaf(wgt, __uint_as_float(hv.y << 16),         acc[2]);
    acc[3] = fmaf(wgt, __uint_as_float(hv.y & 0xffff0000u), acc[3]);
    acc[4] = fmaf(wgt, __uint_as_float(hv.z << 16),         acc[4]);
    acc[5] = fmaf(wgt, __uint_as_float(hv.z & 0xffff0000u), acc[5]);
    acc[6] = fmaf(wgt, __uint_as_float(hv.w << 16),         acc[6]);
    acc[7] = fmaf(wgt, __uint_as_float(hv.w & 0xffff0000u), acc[7]);
}

template <bool LAST>
__global__ __launch_bounds__(256, 8) void prop8(const int* __restrict__ rowptr,
                                                const uint2* __restrict__ edges,
                                                const unsigned short* __restrict__ hin,
                                                const unsigned short* __restrict__ h0b,
                                                unsigned short* __restrict__ hout_b,
                                                float* __restrict__ out_f) {
    int wid = (blockIdx.x * blockDim.x + threadIdx.x) >> 6;
    if (wid >= N_NODES) return;
    int lane = threadIdx.x & 63;
    int slot = lane >> 3;
    int lc   = lane & 7;
    int s = rowptr[wid], e = rowptr[wid + 1];

    float acc0[8], acc1[8];
#pragma unroll
    for (int k = 0; k < 8; ++k) { acc0[k] = 0.f; acc1[k] = 0.f; }

    int i = s;
    for (; i + 32 <= e; i += 32) {
        uint2 cw0 = edges[i + slot];
        uint2 cw1 = edges[i + 8 + slot];
        uint2 cw2 = edges[i + 16 + slot];
        uint2 cw3 = edges[i + 24 + slot];
        uint4 hv0 = *(const uint4*)((const char*)hin + ((size_t)cw0.x << 7) + lc * 16);
        uint4 hv1 = *(const uint4*)((const char*)hin + ((size_t)cw1.x << 7) + lc * 16);
        uint4 hv2 = *(const uint4*)((const char*)hin + ((size_t)cw2.x << 7) + lc * 16);
        uint4 hv3 = *(const uint4*)((const char*)hin + ((size_t)cw3.x << 7) + lc * 16);
        edge_fma(acc0, __uint_as_float(cw0.y), hv0);
        edge_fma(acc1, __uint_as_float(cw1.y), hv1);
        edge_fma(acc0, __uint_as_float(cw2.y), hv2);
        edge_fma(acc1, __uint_as_float(cw3.y), hv3);
    }
    for (; i + 16 <= e; i += 16) {
        uint2 cw0 = edges[i + slot];
        uint2 cw1 = edges[i + 8 + slot];
        uint4 hv0 = *(const uint4*)((const char*)hin + ((size_t)cw0.x << 7) + lc * 16);
        uint4 hv1 = *(const uint4*)((const char*)hin + ((size_t)cw1.x << 7) + lc * 16);
        edge_fma(acc0, __uint_as_float(cw0.y), hv0);
        edge_fma(acc1, __uint_as_float(cw1.y), hv1);
    }
    for (; i < e; i += 8) {
        int idx = i + slot;
        uint2 cw = (idx < e) ? edges[idx] : make_uint2(0u, 0u);
        float wgt = (idx < e) ? __uint_as_float(cw.y) : 0.f;
        uint4 hv = *(const uint4*)((const char*)hin + ((size_t)cw.x << 7) + lc * 16);
        edge_fma(acc0, wgt, hv);
    }

    float r[8];
#pragma unroll
    for (int k = 0; k < 8; ++k) {
        float v = acc0[k] + acc1[k];
        v += __shfl_xor(v, 8, 64);
        v += __shfl_xor(v, 16, 64);
        v += __shfl_xor(v, 32, 64);
        r[k] = v;
    }

    // residual from bf16 h0b (same 8 channels this lane owns)
    uint4 h0v = *(const uint4*)((const char*)h0b + ((size_t)wid << 7) + lc * 16);
    float h0e[8];
    h0e[0] = __uint_as_float(h0v.x << 16);
    h0e[1] = __uint_as_float(h0v.x & 0xffff0000u);
    h0e[2] = __uint_as_float(h0v.y << 16);
    h0e[3] = __uint_as_float(h0v.y & 0xffff0000u);
    h0e[4] = __uint_as_float(h0v.z << 16);
    h0e[5] = __uint_as_float(h0v.z & 0xffff0000u);
    h0e[6] = __uint_as_float(h0v.w << 16);
    h0e[7] = __uint_as_float(h0v.w & 0xffff0000u);
#pragma unroll
    for (int k = 0; k < 8; ++k) r[k] = 0.9f * r[k] + 0.1f * h0e[k];

    if (!LAST) {
        if (slot == 0) {
            uint4 u;
            u.x = ((unsigned)f2bf(r[1]) << 16) | f2bf(r[0]);
            u.y = ((unsigned)f2bf(r[3]) << 16) | f2bf(r[2]);
            u.z = ((unsigned)f2bf(r[5]) << 16) | f2bf(r[4]);
            u.w = ((unsigned)f2bf(r[7]) << 16) | f2bf(r[6]);
            *(uint4*)((char*)hout_b + ((size_t)wid << 7) + lc * 16) = u;
        }
    } else {
        int ch0 = lc * 8;
        float m = -INFINITY;
#pragma unroll
        for (int k = 0; k < 8; ++k) if (ch0 + k < OUT_C) m = fmaxf(m, r[k]);
        m = fmaxf(m, __shfl_xor(m, 1, 64));
        m = fmaxf(m, __shfl_xor(m, 2, 64));
        m = fmaxf(m, __shfl_xor(m, 4, 64));
        float ss = 0.f;
#pragma unroll
        for (int k = 0; k < 8; ++k) if (ch0 + k < OUT_C) ss += __expf(r[k] - m);
        ss += __shfl_xor(ss, 1, 64);
        ss += __shfl_xor(ss, 2, 64);
        ss += __shfl_xor(ss, 4, 64);
        float lse = __logf(ss);
        if (slot == 0) {
#pragma unroll
            for (int k = 0; k < 8; ++k)
                if (ch0 + k < OUT_C)
                    out_f[(size_t)wid * OUT_C + ch0 + k] = (r[k] - m) - lse;
        }
    }
}

// ---------------------------------------------------------------------------
extern "C" void kernel_launch(void* const* d_in, const int* in_sizes, int n_in,
                              void* d_out, int out_size, void* d_ws, size_t ws_size,
                              hipStream_t stream) {
    const float* x    = (const float*)d_in[0];
    const int*   erow = (const int*)d_in[1];
    const int*   ecol = (const int*)d_in[2];
    const float* ew   = (const float*)d_in[3];
    const float* W1   = (const float*)d_in[4];
    const float* b1   = (const float*)d_in[5];
    const float* W2   = (const float*)d_in[6];
    const float* b2   = (const float*)d_in[7];
    float* out = (float*)d_out;

    char* p = (char*)d_ws;
    auto alloc = [&](size_t bytes) {
        char* r = p;
        p += (bytes + 255) & ~(size_t)255;
        return r;
    };
    char*  scratch = alloc((size_t)NBUCK * BCAP * 8);             // 16.1 MB (buckets / ha / hb)
    unsigned short* h0b = (unsigned short*)alloc((size_t)N_NODES * PAD_C * 2); // 6.4 MB
    uint2* edges  = (uint2*)alloc((size_t)N_EDGES * 8);           // 12.8 MB packed CSR
    int*   rowptr = (int*)alloc((size_t)(N_NODES + 1) * 4);
    int*   bfill  = (int*)alloc((size_t)NBUCK * 4);
    int*   bbase  = (int*)alloc((size_t)(NBUCK + 1) * 4);
    float* bp     = (float*)alloc((size_t)PAD_C * 4);
    unsigned short* Wt  = (unsigned short*)alloc((size_t)HID_C * IN_C * 2);
    unsigned short* Wpt = (unsigned short*)alloc((size_t)PAD_C * HID_C * 2);
    // --- aliases onto scratch (sequential lifetimes, stream-ordered):
    uint2* buckets = (uint2*)scratch;                                       // CSR build
    unsigned short* ha = (unsigned short*)scratch;                          // 6.4 MB (prop)
    unsigned short* hb = (unsigned short*)(scratch + (size_t)N_NODES * PAD_C * 2); // 6.4 MB

    hipMemsetAsync(bfill, 0, (size_t)NBUCK * 4, stream);

    // K1: scatter + transpose_w1 + pad_w2 (independent, one launch)
    prep_fused<<<PHB_BLOCKS + TW_BLOCKS + PW_BLOCKS, 256, 0, stream>>>(
        erow, ecol, ew, bfill, buckets, W1, Wt, W2, b2, Wpt, bp);

    bucket_scan<<<1, 128, 0, stream>>>(bfill, bbase, rowptr);

    // K2: bucket_csr (98 blocks) overlapped with gemm (782 blocks)
    csr_gemm_fused<<<NBUCK + GEMM_BLOCKS, 256, 0, stream>>>(
        buckets, bfill, bbase, rowptr, edges,
        x, Wt, b1, Wpt, bp, h0b);

    // Propagation x10: separate launches, wave-per-node, bf16 ping-pong.
    const int prop_blocks = (N_NODES * 64 + 255) / 256;
    const unsigned short* cur = h0b;
    unsigned short* nxt = ha;
    for (int l = 0; l < NUM_LAYERS - 1; ++l) {
        prop8<false><<<prop_blocks, 256, 0, stream>>>(rowptr, edges, cur, h0b,
                                                      nxt, nullptr);
        const unsigned short* t = nxt;
        nxt = (nxt == ha) ? hb : ha;
        cur = t;
    }
    prop8<true><<<prop_blocks, 256, 0, stream>>>(rowptr, edges, cur, h0b,
                                                 nullptr, out);
}